// Round 1
// baseline (685.960 us; speedup 1.0000x reference)
//
#include <hip/hip_runtime.h>

// ImprovedGraphSAGE: 4x SAGEConv(aggr='lstm') on MI355X.
// N=20000 nodes, DEG=16, F_IN=HID=128, OUT=64, E=320000.
//
// Per layer:
//   1) gemm_xw : xW[N,512] = bf16(x @ Wih.T + bih + bhh)        (MFMA bf16)
//   2) lstm_rec: 16-step LSTM over gathered xW rows, Whh in regs (MFMA bf16)
//   3) gemm_out: y = agg@Wl.T + bl + x@Wr.T (+res)(+relu)       (MFMA bf16, K=256)

#define N_NODES 20000
#define DEG 16

typedef __bf16 bf16x8 __attribute__((ext_vector_type(8)));
typedef float f32x4 __attribute__((ext_vector_type(4)));

__device__ inline unsigned short f2bf(float f) {
  unsigned u = __builtin_bit_cast(unsigned, f);
  u += 0x7fffu + ((u >> 16) & 1u);
  return (unsigned short)(u >> 16);
}
__device__ inline float bf2f(unsigned short s) {
  return __builtin_bit_cast(float, ((unsigned)s) << 16);
}
__device__ inline float fexp2(float x) {
#if __has_builtin(__builtin_amdgcn_exp2f)
  return __builtin_amdgcn_exp2f(x);
#else
  return exp2f(x);
#endif
}
__device__ inline float frcp(float x) {
#if __has_builtin(__builtin_amdgcn_rcpf)
  return __builtin_amdgcn_rcpf(x);
#else
  return 1.f / x;
#endif
}
__device__ inline float sigm(float x) { return frcp(1.f + fexp2(-1.44269504f * x)); }
__device__ inline float tanh_(float x) { return frcp(1.f + fexp2(-2.88539008f * x)) * 2.f - 1.f; }

__device__ inline bf16x8 load_w8(const float* p) {
  float4 a = *(const float4*)p;
  float4 b = *(const float4*)(p + 4);
  bf16x8 v;
  v[0] = (__bf16)a.x; v[1] = (__bf16)a.y; v[2] = (__bf16)a.z; v[3] = (__bf16)a.w;
  v[4] = (__bf16)b.x; v[5] = (__bf16)b.y; v[6] = (__bf16)b.z; v[7] = (__bf16)b.w;
  return v;
}

// ---------------------------------------------------------------------------
// Kernel 1: xW[N,512](bf16) = x[N,128] @ Wih.T + (bih+bhh)
// Tile: 64 rows x 64 cols per WG, 4 waves (each wave owns 16 cols).
// ---------------------------------------------------------------------------
__global__ __launch_bounds__(256) void gemm_xw(
    const float* __restrict__ X, const float* __restrict__ Wih,
    const float* __restrict__ bih, const float* __restrict__ bhh,
    unsigned short* __restrict__ xW, int Nrows) {
  __shared__ __align__(16) unsigned char As[64 * 256];  // [64 rows][128 bf16], swizzled
  const int tid = threadIdx.x;
  const int lane = tid & 63, w = tid >> 6;
  const int l15 = lane & 15, l4 = lane >> 4;
  const int row0 = blockIdx.x * 64;

  // stage A tile (fp32 -> bf16), coalesced float4 loads
#pragma unroll
  for (int i = 0; i < 8; ++i) {
    int flat = i * 1024 + tid * 4;           // 0..8191
    int r = flat >> 7, c = flat & 127;
    int grow = row0 + r;
    float4 v = (grow < Nrows) ? *(const float4*)(X + grow * 128 + c)
                              : make_float4(0.f, 0.f, 0.f, 0.f);
    ushort4 b;
    b.x = f2bf(v.x); b.y = f2bf(v.y); b.z = f2bf(v.z); b.w = f2bf(v.w);
    int byte = (r * 256 + c * 2) ^ ((r & 7) << 4);
    *(ushort4*)(As + byte) = b;
  }
  __syncthreads();

  const int colg = blockIdx.y * 64 + w * 16 + l15;
  bf16x8 bw[4];
#pragma unroll
  for (int kt = 0; kt < 4; ++kt)
    bw[kt] = load_w8(Wih + colg * 128 + kt * 32 + l4 * 8);

  f32x4 acc[4];
#pragma unroll
  for (int rt = 0; rt < 4; ++rt) acc[rt] = (f32x4){0.f, 0.f, 0.f, 0.f};

#pragma unroll
  for (int kt = 0; kt < 4; ++kt) {
#pragma unroll
    for (int rt = 0; rt < 4; ++rt) {
      int m = rt * 16 + l15;
      int byte = (m * 256 + kt * 64 + l4 * 16) ^ ((m & 7) << 4);
      bf16x8 af = *(const bf16x8*)(As + byte);
      acc[rt] = __builtin_amdgcn_mfma_f32_16x16x32_bf16(af, bw[kt], acc[rt], 0, 0, 0);
    }
  }

  const float bias = bih[colg] + bhh[colg];
#pragma unroll
  for (int rt = 0; rt < 4; ++rt)
#pragma unroll
    for (int r = 0; r < 4; ++r) {
      int grow = row0 + rt * 16 + l4 * 4 + r;
      if (grow < Nrows) xW[grow * 512 + colg] = f2bf(acc[rt][r] + bias);
    }
}

// ---------------------------------------------------------------------------
// Kernel 2: LSTM recurrence. WG = 32 nodes, 8 waves; wave w owns h-cols
// [w*16, w*16+16). Whh B-fragments in registers (16 frags = 64 VGPR).
// h round-trips through swizzled LDS each step; c stays in registers.
// ---------------------------------------------------------------------------
__global__ __launch_bounds__(512, 2) void lstm_rec(
    const unsigned short* __restrict__ xW,  // [N,512] bf16
    const int* __restrict__ src,            // [E]
    const float* __restrict__ Whh,          // [512,128] fp32
    float* __restrict__ agg) {              // [N,128] fp32
  __shared__ __align__(16) unsigned char hbuf[32 * 256];  // [32 nodes][128 bf16], swizzled
  __shared__ __align__(16) int idx_s[512];                // idx_s[t*32 + node_local]
  const int tid = threadIdx.x;
  const int lane = tid & 63, w = tid >> 6;
  const int l15 = lane & 15, l4 = lane >> 4;
  const int node0 = blockIdx.x * 32;

  // Whh B-fragments: B[k][n] = Whh[gate*128 + w*16 + (lane&15)][k]
  bf16x8 bw[4][4];
#pragma unroll
  for (int g = 0; g < 4; ++g)
#pragma unroll
    for (int kt = 0; kt < 4; ++kt)
      bw[g][kt] = load_w8(Whh + (g * 128 + w * 16 + l15) * 128 + kt * 32 + l4 * 8);

  // stage edge indices transposed: idx_s[t*32 + nl]
  idx_s[(tid & 15) * 32 + (tid >> 4)] = src[node0 * DEG + tid];
  // zero h
  *(uint4*)(hbuf + tid * 16) = make_uint4(0, 0, 0, 0);
  __syncthreads();

  float c[2][4] = {{0.f, 0.f, 0.f, 0.f}, {0.f, 0.f, 0.f, 0.f}};

  for (int t = 0; t < 16; ++t) {
    // neighbor indices for this step (broadcast-friendly LDS reads)
    int ia[2][4];
#pragma unroll
    for (int rt = 0; rt < 2; ++rt) {
      int4 q = *(const int4*)(idx_s + t * 32 + rt * 16 + l4 * 4);
      ia[rt][0] = q.x; ia[rt][1] = q.y; ia[rt][2] = q.z; ia[rt][3] = q.w;
    }
    // gather xW rows (issued early; consumed after MFMA block)
    unsigned short xg[2][4][4];
#pragma unroll
    for (int rt = 0; rt < 2; ++rt)
#pragma unroll
      for (int r = 0; r < 4; ++r) {
        const unsigned short* rp = xW + ia[rt][r] * 512 + w * 16 + l15;
#pragma unroll
        for (int g = 0; g < 4; ++g) xg[rt][g][r] = rp[g * 128];
      }

    f32x4 acc[2][4];
#pragma unroll
    for (int rt = 0; rt < 2; ++rt)
#pragma unroll
      for (int g = 0; g < 4; ++g) acc[rt][g] = (f32x4){0.f, 0.f, 0.f, 0.f};

    if (t > 0) {  // h == 0 at t==0
      bf16x8 af[2][4];
#pragma unroll
      for (int rt = 0; rt < 2; ++rt)
#pragma unroll
        for (int kt = 0; kt < 4; ++kt) {
          int m = rt * 16 + l15;
          int byte = (m * 256 + kt * 64 + l4 * 16) ^ ((m & 7) << 4);
          af[rt][kt] = *(const bf16x8*)(hbuf + byte);
        }
#pragma unroll
      for (int rt = 0; rt < 2; ++rt)
#pragma unroll
        for (int g = 0; g < 4; ++g)
#pragma unroll
          for (int kt = 0; kt < 4; ++kt)
            acc[rt][g] = __builtin_amdgcn_mfma_f32_16x16x32_bf16(af[rt][kt], bw[g][kt],
                                                                 acc[rt][g], 0, 0, 0);
    }

    // gates + state update (lane-local; gate tiles share C/D lane mapping)
    float hn[2][4];
#pragma unroll
    for (int rt = 0; rt < 2; ++rt)
#pragma unroll
      for (int r = 0; r < 4; ++r) {
        float pi = acc[rt][0][r] + bf2f(xg[rt][0][r]);
        float pf = acc[rt][1][r] + bf2f(xg[rt][1][r]);
        float pg = acc[rt][2][r] + bf2f(xg[rt][2][r]);
        float po = acc[rt][3][r] + bf2f(xg[rt][3][r]);
        float ig = sigm(pi), fg = sigm(pf), gg = tanh_(pg), og = sigm(po);
        float cn = fg * c[rt][r] + ig * gg;
        c[rt][r] = cn;
        hn[rt][r] = og * tanh_(cn);
      }

    if (t < 15) {
      __syncthreads();  // all waves done reading h_{t-1}
#pragma unroll
      for (int rt = 0; rt < 2; ++rt)
#pragma unroll
        for (int r = 0; r < 4; ++r) {
          int m = rt * 16 + l4 * 4 + r;
          int byte = (m * 256 + (w * 16 + l15) * 2) ^ ((m & 7) << 4);
          *(unsigned short*)(hbuf + byte) = f2bf(hn[rt][r]);
        }
      __syncthreads();  // h_t visible to all
    } else {
#pragma unroll
      for (int rt = 0; rt < 2; ++rt)
#pragma unroll
        for (int r = 0; r < 4; ++r) {
          int m = rt * 16 + l4 * 4 + r;
          agg[(node0 + m) * 128 + w * 16 + l15] = hn[rt][r];
        }
    }
  }
}

// ---------------------------------------------------------------------------
// Kernel 3: out[N,NOUT] = agg@Wl.T + bl + x@Wr.T (+resid) (+relu)
// Treated as one K=256 GEMM with A = [agg | x], B = [Wl | Wr].
// ---------------------------------------------------------------------------
__global__ __launch_bounds__(256) void gemm_out(
    const float* __restrict__ A1,   // agg [N,128]
    const float* __restrict__ A2,   // x   [N,128]
    const float* __restrict__ Wl, const float* __restrict__ bl,
    const float* __restrict__ Wr,
    const float* __restrict__ resid,  // nullptr or [N,128]
    float* __restrict__ out, int NOUT, int do_relu, int Nrows) {
  __shared__ __align__(16) unsigned char As[64 * 512];  // [64 rows][256 bf16], swizzled
  const int tid = threadIdx.x;
  const int lane = tid & 63, w = tid >> 6;
  const int l15 = lane & 15, l4 = lane >> 4;
  const int row0 = blockIdx.x * 64;

#pragma unroll
  for (int i = 0; i < 16; ++i) {
    int flat = i * 1024 + tid * 4;  // 0..16383
    int r = flat >> 8, c = flat & 255;
    int grow = row0 + r;
    float4 v;
    if (grow < Nrows)
      v = (c < 128) ? *(const float4*)(A1 + grow * 128 + c)
                    : *(const float4*)(A2 + grow * 128 + (c - 128));
    else
      v = make_float4(0.f, 0.f, 0.f, 0.f);
    ushort4 b;
    b.x = f2bf(v.x); b.y = f2bf(v.y); b.z = f2bf(v.z); b.w = f2bf(v.w);
    int byte = (r * 512 + c * 2) ^ ((r & 7) << 4);
    *(ushort4*)(As + byte) = b;
  }
  __syncthreads();

  const int colg = blockIdx.y * 64 + w * 16 + l15;
  bf16x8 bw[8];
#pragma unroll
  for (int kt = 0; kt < 8; ++kt) {
    const float* bp = (kt < 4) ? (Wl + colg * 128 + kt * 32 + l4 * 8)
                               : (Wr + colg * 128 + (kt - 4) * 32 + l4 * 8);
    bw[kt] = load_w8(bp);
  }

  f32x4 acc[4];
#pragma unroll
  for (int rt = 0; rt < 4; ++rt) acc[rt] = (f32x4){0.f, 0.f, 0.f, 0.f};

#pragma unroll
  for (int kt = 0; kt < 8; ++kt) {
#pragma unroll
    for (int rt = 0; rt < 4; ++rt) {
      int m = rt * 16 + l15;
      int byte = (m * 512 + kt * 64 + l4 * 16) ^ ((m & 7) << 4);
      bf16x8 af = *(const bf16x8*)(As + byte);
      acc[rt] = __builtin_amdgcn_mfma_f32_16x16x32_bf16(af, bw[kt], acc[rt], 0, 0, 0);
    }
  }

  const float bias = bl[colg];
#pragma unroll
  for (int rt = 0; rt < 4; ++rt)
#pragma unroll
    for (int r = 0; r < 4; ++r) {
      int grow = row0 + rt * 16 + l4 * 4 + r;
      if (grow < Nrows) {
        float v = acc[rt][r] + bias;
        if (resid) v += resid[grow * 128 + colg];
        if (do_relu) v = fmaxf(v, 0.f);
        out[grow * NOUT + colg] = v;
      }
    }
}

// ---------------------------------------------------------------------------
extern "C" void kernel_launch(void* const* d_in, const int* in_sizes, int n_in,
                              void* d_out, int out_size, void* d_ws, size_t ws_size,
                              hipStream_t stream) {
  const float* X = (const float*)d_in[0];
  const int* src = (const int*)d_in[1];  // edge_index[0] = first E ints
  const float* Wih = (const float*)d_in[2];
  const float* Whh = (const float*)d_in[3];
  const float* bih = (const float*)d_in[4];
  const float* bhh = (const float*)d_in[5];
  const float* Wl123 = (const float*)d_in[6];
  const float* bl123 = (const float*)d_in[7];
  const float* Wr123 = (const float*)d_in[8];
  const float* Wl4 = (const float*)d_in[9];
  const float* bl4 = (const float*)d_in[10];
  const float* Wr4 = (const float*)d_in[11];
  float* out = (float*)d_out;

  char* ws = (char*)d_ws;
  unsigned short* xW = (unsigned short*)ws;                       // 20.48 MB
  float* agg = (float*)(ws + 20480000);                           // 10.24 MB
  float* xb0 = (float*)(ws + 20480000 + 10240000);                // 10.24 MB
  float* xb1 = (float*)(ws + 20480000 + 2 * 10240000);            // 10.24 MB

  const float* xcur = X;
  for (int L = 0; L < 4; ++L) {
    gemm_xw<<<dim3(313, 8), 256, 0, stream>>>(xcur, Wih + L * 65536, bih + L * 512,
                                              bhh + L * 512, xW, N_NODES);
    lstm_rec<<<dim3(625), 512, 0, stream>>>(xW, src, Whh + L * 65536, agg);
    if (L < 3) {
      float* nxt = (L & 1) ? xb1 : xb0;
      gemm_out<<<dim3(313, 2), 256, 0, stream>>>(agg, xcur, Wl123 + L * 16384,
                                                 bl123 + L * 128, Wr123 + L * 16384,
                                                 (L >= 1) ? xcur : nullptr, nxt, 128, 1,
                                                 N_NODES);
      xcur = nxt;
    } else {
      gemm_out<<<dim3(313, 1), 256, 0, stream>>>(agg, xcur, Wl4, bl4, Wr4, nullptr, out,
                                                 64, 0, N_NODES);
    }
  }
}

// Round 2
// 615.196 us; speedup vs baseline: 1.1150x; 1.1150x over previous
//
#include <hip/hip_runtime.h>

// ImprovedGraphSAGE: 4x SAGEConv(aggr='lstm') on MI355X.
// N=20000 nodes, DEG=16, F_IN=HID=128, OUT=64, E=320000.
//
// Per layer:
//   1) gemm_xw : xW4[N][128][4] = bf16(x @ Wih.T + bih + bhh), gate-interleaved
//   2) lstm_rec: 16-step LSTM over gathered xW4 rows, Whh in regs (MFMA bf16)
//      16 nodes/block, 8 waves, ushort4 gather + next-step prefetch
//   3) gemm_out: y = agg@Wl.T + bl + x@Wr.T (+res)(+relu)       (MFMA bf16, K=256)

#define N_NODES 20000
#define DEG 16

typedef __bf16 bf16x8 __attribute__((ext_vector_type(8)));
typedef float f32x4 __attribute__((ext_vector_type(4)));

__device__ inline unsigned short f2bf(float f) {
  unsigned u = __builtin_bit_cast(unsigned, f);
  u += 0x7fffu + ((u >> 16) & 1u);
  return (unsigned short)(u >> 16);
}
__device__ inline float bf2f(unsigned short s) {
  return __builtin_bit_cast(float, ((unsigned)s) << 16);
}
__device__ inline float fexp2(float x) {
#if __has_builtin(__builtin_amdgcn_exp2f)
  return __builtin_amdgcn_exp2f(x);
#else
  return exp2f(x);
#endif
}
__device__ inline float frcp(float x) {
#if __has_builtin(__builtin_amdgcn_rcpf)
  return __builtin_amdgcn_rcpf(x);
#else
  return 1.f / x;
#endif
}
__device__ inline float sigm(float x) { return frcp(1.f + fexp2(-1.44269504f * x)); }
__device__ inline float tanh_(float x) { return frcp(1.f + fexp2(-2.88539008f * x)) * 2.f - 1.f; }

__device__ inline bf16x8 load_w8(const float* p) {
  float4 a = *(const float4*)p;
  float4 b = *(const float4*)(p + 4);
  bf16x8 v;
  v[0] = (__bf16)a.x; v[1] = (__bf16)a.y; v[2] = (__bf16)a.z; v[3] = (__bf16)a.w;
  v[4] = (__bf16)b.x; v[5] = (__bf16)b.y; v[6] = (__bf16)b.z; v[7] = (__bf16)b.w;
  return v;
}

// ---------------------------------------------------------------------------
// Kernel 1: xW4[N][128][4](bf16) = x[N,128] @ Wih.T + (bih+bhh), gates packed
// innermost so the LSTM gather reads one ushort4 per (node,col).
// Tile: 64 rows x 64 hid-cols (x4 gates) per WG, 4 waves (wave: 16 hid-cols).
// ---------------------------------------------------------------------------
__global__ __launch_bounds__(256) void gemm_xw(
    const float* __restrict__ X, const float* __restrict__ Wih,
    const float* __restrict__ bih, const float* __restrict__ bhh,
    unsigned short* __restrict__ xW4, int Nrows) {
  __shared__ __align__(16) unsigned char As[64 * 256];  // [64 rows][128 bf16], swizzled
  const int tid = threadIdx.x;
  const int lane = tid & 63, w = tid >> 6;
  const int l15 = lane & 15, l4 = lane >> 4;
  const int row0 = blockIdx.x * 64;

  // stage A tile (fp32 -> bf16), coalesced float4 loads
#pragma unroll
  for (int i = 0; i < 8; ++i) {
    int flat = i * 1024 + tid * 4;           // 0..8191
    int r = flat >> 7, c = flat & 127;
    int grow = row0 + r;
    float4 v = (grow < Nrows) ? *(const float4*)(X + grow * 128 + c)
                              : make_float4(0.f, 0.f, 0.f, 0.f);
    ushort4 b;
    b.x = f2bf(v.x); b.y = f2bf(v.y); b.z = f2bf(v.z); b.w = f2bf(v.w);
    int byte = (r * 256 + c * 2) ^ ((r & 7) << 4);
    *(ushort4*)(As + byte) = b;
  }
  __syncthreads();

  const int colc = blockIdx.y * 64 + w * 16 + l15;  // hid col 0..127
  bf16x8 bw[4][4];
#pragma unroll
  for (int g = 0; g < 4; ++g)
#pragma unroll
    for (int kt = 0; kt < 4; ++kt)
      bw[g][kt] = load_w8(Wih + (g * 128 + colc) * 128 + kt * 32 + l4 * 8);
  float bsum[4];
#pragma unroll
  for (int g = 0; g < 4; ++g) bsum[g] = bih[g * 128 + colc] + bhh[g * 128 + colc];

  f32x4 acc[4][4];  // [rt][gate]
#pragma unroll
  for (int rt = 0; rt < 4; ++rt)
#pragma unroll
    for (int g = 0; g < 4; ++g) acc[rt][g] = (f32x4){0.f, 0.f, 0.f, 0.f};

#pragma unroll
  for (int rt = 0; rt < 4; ++rt) {
    bf16x8 af[4];
#pragma unroll
    for (int kt = 0; kt < 4; ++kt) {
      int m = rt * 16 + l15;
      int byte = (m * 256 + kt * 64 + l4 * 16) ^ ((m & 7) << 4);
      af[kt] = *(const bf16x8*)(As + byte);
    }
#pragma unroll
    for (int g = 0; g < 4; ++g)
#pragma unroll
      for (int kt = 0; kt < 4; ++kt)
        acc[rt][g] = __builtin_amdgcn_mfma_f32_16x16x32_bf16(af[kt], bw[g][kt],
                                                             acc[rt][g], 0, 0, 0);
  }

#pragma unroll
  for (int rt = 0; rt < 4; ++rt)
#pragma unroll
    for (int r = 0; r < 4; ++r) {
      int grow = row0 + rt * 16 + l4 * 4 + r;
      if (grow < Nrows) {
        ushort4 o;
        o.x = f2bf(acc[rt][0][r] + bsum[0]);
        o.y = f2bf(acc[rt][1][r] + bsum[1]);
        o.z = f2bf(acc[rt][2][r] + bsum[2]);
        o.w = f2bf(acc[rt][3][r] + bsum[3]);
        *(ushort4*)(xW4 + grow * 512 + colc * 4) = o;
      }
    }
}

// ---------------------------------------------------------------------------
// Kernel 2: LSTM recurrence. WG = 16 nodes, 8 waves; wave w owns h-cols
// [w*16, w*16+16). Whh B-fragments in registers (16 frags = 64 VGPR).
// h round-trips through swizzled LDS each step; c stays in registers.
// Gather: one ushort4 (4 gates) per (node,col); next step prefetched.
// ---------------------------------------------------------------------------
__global__ __launch_bounds__(512) void lstm_rec(
    const unsigned short* __restrict__ xW4,  // [N][128][4] bf16
    const int* __restrict__ src,             // [E]
    const float* __restrict__ Whh,           // [512,128] fp32
    float* __restrict__ agg) {               // [N,128] fp32
  __shared__ __align__(16) unsigned char hbuf[16 * 256];  // [16 nodes][128 bf16], swizzled
  __shared__ __align__(16) int idx_s[256];                // idx_s[t*16 + node_local]
  const int tid = threadIdx.x;
  const int lane = tid & 63, w = tid >> 6;
  const int l15 = lane & 15, l4 = lane >> 4;
  const int node0 = blockIdx.x * 16;
  const int colb = w * 16 + l15;  // this lane's h-column

  // Whh B-fragments: B[k][n] = Whh[gate*128 + colb][k]
  bf16x8 bw[4][4];
#pragma unroll
  for (int g = 0; g < 4; ++g)
#pragma unroll
    for (int kt = 0; kt < 4; ++kt)
      bw[g][kt] = load_w8(Whh + (g * 128 + colb) * 128 + kt * 32 + l4 * 8);

  // stage edge indices transposed: idx_s[t*16 + node_local]
  if (tid < 256) idx_s[(tid & 15) * 16 + (tid >> 4)] = src[node0 * DEG + tid];
  __syncthreads();

  float c[4] = {0.f, 0.f, 0.f, 0.f};
  ushort4 xg[4], xgn[4];

  // gather for t=0: lane (l4,l15) loads 4 gate values of node l4*4+r, col colb
  {
    int4 q = *(const int4*)(idx_s + l4 * 4);
#pragma unroll
    for (int r = 0; r < 4; ++r) {
      int ia = (r == 0) ? q.x : (r == 1) ? q.y : (r == 2) ? q.z : q.w;
      xg[r] = *(const ushort4*)(xW4 + ia * 512 + colb * 4);
    }
  }

#pragma unroll
  for (int t = 0; t < 16; ++t) {
    // prefetch next step's gather (consumed next iteration)
    if (t < 15) {
      int4 q = *(const int4*)(idx_s + (t + 1) * 16 + l4 * 4);
#pragma unroll
      for (int r = 0; r < 4; ++r) {
        int ia = (r == 0) ? q.x : (r == 1) ? q.y : (r == 2) ? q.z : q.w;
        xgn[r] = *(const ushort4*)(xW4 + ia * 512 + colb * 4);
      }
    }

    f32x4 acc[4];
#pragma unroll
    for (int g = 0; g < 4; ++g) acc[g] = (f32x4){0.f, 0.f, 0.f, 0.f};

    if (t > 0) {  // h == 0 at t==0
      bf16x8 af[4];
#pragma unroll
      for (int kt = 0; kt < 4; ++kt) {
        int byte = (l15 * 256 + kt * 64 + l4 * 16) ^ ((l15 & 7) << 4);
        af[kt] = *(const bf16x8*)(hbuf + byte);
      }
#pragma unroll
      for (int g = 0; g < 4; ++g)
#pragma unroll
        for (int kt = 0; kt < 4; ++kt)
          acc[g] = __builtin_amdgcn_mfma_f32_16x16x32_bf16(af[kt], bw[g][kt],
                                                           acc[g], 0, 0, 0);
    }

    // gates + state update (lane-local; gate tiles share C/D lane mapping)
    float hn[4];
#pragma unroll
    for (int r = 0; r < 4; ++r) {
      float pi = acc[0][r] + bf2f(xg[r].x);
      float pf = acc[1][r] + bf2f(xg[r].y);
      float pg = acc[2][r] + bf2f(xg[r].z);
      float po = acc[3][r] + bf2f(xg[r].w);
      float ig = sigm(pi), fg = sigm(pf), gg = tanh_(pg), og = sigm(po);
      float cn = fg * c[r] + ig * gg;
      c[r] = cn;
      hn[r] = og * tanh_(cn);
    }

    if (t < 15) {
      __syncthreads();  // all waves done reading h_{t-1}
#pragma unroll
      for (int r = 0; r < 4; ++r) {
        int m = l4 * 4 + r;
        int byte = (m * 256 + colb * 2) ^ ((m & 7) << 4);
        *(unsigned short*)(hbuf + byte) = f2bf(hn[r]);
      }
      __syncthreads();  // h_t visible to all
#pragma unroll
      for (int r = 0; r < 4; ++r) xg[r] = xgn[r];
    } else {
#pragma unroll
      for (int r = 0; r < 4; ++r)
        agg[(node0 + l4 * 4 + r) * 128 + colb] = hn[r];
    }
  }
}

// ---------------------------------------------------------------------------
// Kernel 3: out[N,NOUT] = agg@Wl.T + bl + x@Wr.T (+resid) (+relu)
// Treated as one K=256 GEMM with A = [agg | x], B = [Wl | Wr].
// ---------------------------------------------------------------------------
__global__ __launch_bounds__(256) void gemm_out(
    const float* __restrict__ A1,   // agg [N,128]
    const float* __restrict__ A2,   // x   [N,128]
    const float* __restrict__ Wl, const float* __restrict__ bl,
    const float* __restrict__ Wr,
    const float* __restrict__ resid,  // nullptr or [N,128]
    float* __restrict__ out, int NOUT, int do_relu, int Nrows) {
  __shared__ __align__(16) unsigned char As[64 * 512];  // [64 rows][256 bf16], swizzled
  const int tid = threadIdx.x;
  const int lane = tid & 63, w = tid >> 6;
  const int l15 = lane & 15, l4 = lane >> 4;
  const int row0 = blockIdx.x * 64;

#pragma unroll
  for (int i = 0; i < 16; ++i) {
    int flat = i * 1024 + tid * 4;  // 0..16383
    int r = flat >> 8, c = flat & 255;
    int grow = row0 + r;
    float4 v;
    if (grow < Nrows)
      v = (c < 128) ? *(const float4*)(A1 + grow * 128 + c)
                    : *(const float4*)(A2 + grow * 128 + (c - 128));
    else
      v = make_float4(0.f, 0.f, 0.f, 0.f);
    ushort4 b;
    b.x = f2bf(v.x); b.y = f2bf(v.y); b.z = f2bf(v.z); b.w = f2bf(v.w);
    int byte = (r * 512 + c * 2) ^ ((r & 7) << 4);
    *(ushort4*)(As + byte) = b;
  }
  __syncthreads();

  const int colg = blockIdx.y * 64 + w * 16 + l15;
  bf16x8 bw[8];
#pragma unroll
  for (int kt = 0; kt < 8; ++kt) {
    const float* bp = (kt < 4) ? (Wl + colg * 128 + kt * 32 + l4 * 8)
                               : (Wr + colg * 128 + (kt - 4) * 32 + l4 * 8);
    bw[kt] = load_w8(bp);
  }

  f32x4 acc[4];
#pragma unroll
  for (int rt = 0; rt < 4; ++rt) acc[rt] = (f32x4){0.f, 0.f, 0.f, 0.f};

#pragma unroll
  for (int kt = 0; kt < 8; ++kt) {
#pragma unroll
    for (int rt = 0; rt < 4; ++rt) {
      int m = rt * 16 + l15;
      int byte = (m * 512 + kt * 64 + l4 * 16) ^ ((m & 7) << 4);
      bf16x8 af = *(const bf16x8*)(As + byte);
      acc[rt] = __builtin_amdgcn_mfma_f32_16x16x32_bf16(af, bw[kt], acc[rt], 0, 0, 0);
    }
  }

  const float bias = bl[colg];
#pragma unroll
  for (int rt = 0; rt < 4; ++rt)
#pragma unroll
    for (int r = 0; r < 4; ++r) {
      int grow = row0 + rt * 16 + l4 * 4 + r;
      if (grow < Nrows) {
        float v = acc[rt][r] + bias;
        if (resid) v += resid[grow * 128 + colg];
        if (do_relu) v = fmaxf(v, 0.f);
        out[grow * NOUT + colg] = v;
      }
    }
}

// ---------------------------------------------------------------------------
extern "C" void kernel_launch(void* const* d_in, const int* in_sizes, int n_in,
                              void* d_out, int out_size, void* d_ws, size_t ws_size,
                              hipStream_t stream) {
  const float* X = (const float*)d_in[0];
  const int* src = (const int*)d_in[1];  // edge_index[0] = first E ints
  const float* Wih = (const float*)d_in[2];
  const float* Whh = (const float*)d_in[3];
  const float* bih = (const float*)d_in[4];
  const float* bhh = (const float*)d_in[5];
  const float* Wl123 = (const float*)d_in[6];
  const float* bl123 = (const float*)d_in[7];
  const float* Wr123 = (const float*)d_in[8];
  const float* Wl4 = (const float*)d_in[9];
  const float* bl4 = (const float*)d_in[10];
  const float* Wr4 = (const float*)d_in[11];
  float* out = (float*)d_out;

  char* ws = (char*)d_ws;
  unsigned short* xW4 = (unsigned short*)ws;                      // 20.48 MB
  float* agg = (float*)(ws + 20480000);                           // 10.24 MB
  float* xb0 = (float*)(ws + 20480000 + 10240000);                // 10.24 MB
  float* xb1 = (float*)(ws + 20480000 + 2 * 10240000);            // 10.24 MB

  const float* xcur = X;
  for (int L = 0; L < 4; ++L) {
    gemm_xw<<<dim3(313, 2), 256, 0, stream>>>(xcur, Wih + L * 65536, bih + L * 512,
                                              bhh + L * 512, xW4, N_NODES);
    lstm_rec<<<dim3(1250), 512, 0, stream>>>(xW4, src, Whh + L * 65536, agg);
    if (L < 3) {
      float* nxt = (L & 1) ? xb1 : xb0;
      gemm_out<<<dim3(313, 2), 256, 0, stream>>>(agg, xcur, Wl123 + L * 16384,
                                                 bl123 + L * 128, Wr123 + L * 16384,
                                                 (L >= 1) ? xcur : nullptr, nxt, 128, 1,
                                                 N_NODES);
      xcur = nxt;
    } else {
      gemm_out<<<dim3(313, 1), 256, 0, stream>>>(agg, xcur, Wl4, bl4, Wr4, nullptr, out,
                                                 64, 0, N_NODES);
    }
  }
}

// Round 3
// 597.851 us; speedup vs baseline: 1.1474x; 1.0290x over previous
//
#include <hip/hip_runtime.h>

// ImprovedGraphSAGE: 4x SAGEConv(aggr='lstm') on MI355X.
// N=20000 nodes, DEG=16, F_IN=HID=128, OUT=64, E=320000.
//
// Per layer:
//   1) gemm_xw : xW4[N][128][4] = bf16(x @ Wih.T + bih + bhh), gate-interleaved
//   2) lstm_rec: 16-step LSTM, Whh in regs, depth-3 gather prefetch,
//      double-buffered h in LDS (1 barrier/step), acc init = xW preact
//   3) gemm_out: y = agg@Wl.T + bl + x@Wr.T (+res)(+relu)       (MFMA bf16, K=256)

#define N_NODES 20000
#define DEG 16

typedef __bf16 bf16x8 __attribute__((ext_vector_type(8)));
typedef float f32x4 __attribute__((ext_vector_type(4)));

__device__ inline unsigned short f2bf(float f) {
  unsigned u = __builtin_bit_cast(unsigned, f);
  u += 0x7fffu + ((u >> 16) & 1u);
  return (unsigned short)(u >> 16);
}
__device__ inline float fexp2(float x) {
#if __has_builtin(__builtin_amdgcn_exp2f)
  return __builtin_amdgcn_exp2f(x);
#else
  return exp2f(x);
#endif
}
__device__ inline float frcp(float x) {
#if __has_builtin(__builtin_amdgcn_rcpf)
  return __builtin_amdgcn_rcpf(x);
#else
  return 1.f / x;
#endif
}
__device__ inline float sigm(float x) { return frcp(1.f + fexp2(-1.44269504f * x)); }
__device__ inline float tanh_(float x) { return frcp(1.f + fexp2(-2.88539008f * x)) * 2.f - 1.f; }

__device__ inline bf16x8 load_w8(const float* p) {
  float4 a = *(const float4*)p;
  float4 b = *(const float4*)(p + 4);
  bf16x8 v;
  v[0] = (__bf16)a.x; v[1] = (__bf16)a.y; v[2] = (__bf16)a.z; v[3] = (__bf16)a.w;
  v[4] = (__bf16)b.x; v[5] = (__bf16)b.y; v[6] = (__bf16)b.z; v[7] = (__bf16)b.w;
  return v;
}

// ---------------------------------------------------------------------------
// Kernel 1: xW4[N][128][4](bf16) = x[N,128] @ Wih.T + (bih+bhh), gates packed
// innermost so the LSTM gather reads one ushort4 per (node,col).
// ---------------------------------------------------------------------------
__global__ __launch_bounds__(256) void gemm_xw(
    const float* __restrict__ X, const float* __restrict__ Wih,
    const float* __restrict__ bih, const float* __restrict__ bhh,
    unsigned short* __restrict__ xW4, int Nrows) {
  __shared__ __align__(16) unsigned char As[64 * 256];  // [64 rows][128 bf16], swizzled
  const int tid = threadIdx.x;
  const int lane = tid & 63, w = tid >> 6;
  const int l15 = lane & 15, l4 = lane >> 4;
  const int row0 = blockIdx.x * 64;

#pragma unroll
  for (int i = 0; i < 8; ++i) {
    int flat = i * 1024 + tid * 4;           // 0..8191
    int r = flat >> 7, c = flat & 127;
    int grow = row0 + r;
    float4 v = (grow < Nrows) ? *(const float4*)(X + grow * 128 + c)
                              : make_float4(0.f, 0.f, 0.f, 0.f);
    ushort4 b;
    b.x = f2bf(v.x); b.y = f2bf(v.y); b.z = f2bf(v.z); b.w = f2bf(v.w);
    int byte = (r * 256 + c * 2) ^ ((r & 7) << 4);
    *(ushort4*)(As + byte) = b;
  }
  __syncthreads();

  const int colc = blockIdx.y * 64 + w * 16 + l15;  // hid col 0..127
  bf16x8 bw[4][4];
#pragma unroll
  for (int g = 0; g < 4; ++g)
#pragma unroll
    for (int kt = 0; kt < 4; ++kt)
      bw[g][kt] = load_w8(Wih + (g * 128 + colc) * 128 + kt * 32 + l4 * 8);
  float bsum[4];
#pragma unroll
  for (int g = 0; g < 4; ++g) bsum[g] = bih[g * 128 + colc] + bhh[g * 128 + colc];

  f32x4 acc[4][4];  // [rt][gate]
#pragma unroll
  for (int rt = 0; rt < 4; ++rt)
#pragma unroll
    for (int g = 0; g < 4; ++g) acc[rt][g] = (f32x4){0.f, 0.f, 0.f, 0.f};

#pragma unroll
  for (int rt = 0; rt < 4; ++rt) {
    bf16x8 af[4];
#pragma unroll
    for (int kt = 0; kt < 4; ++kt) {
      int m = rt * 16 + l15;
      int byte = (m * 256 + kt * 64 + l4 * 16) ^ ((m & 7) << 4);
      af[kt] = *(const bf16x8*)(As + byte);
    }
#pragma unroll
    for (int g = 0; g < 4; ++g)
#pragma unroll
      for (int kt = 0; kt < 4; ++kt)
        acc[rt][g] = __builtin_amdgcn_mfma_f32_16x16x32_bf16(af[kt], bw[g][kt],
                                                             acc[rt][g], 0, 0, 0);
  }

#pragma unroll
  for (int rt = 0; rt < 4; ++rt)
#pragma unroll
    for (int r = 0; r < 4; ++r) {
      int grow = row0 + rt * 16 + l4 * 4 + r;
      if (grow < Nrows) {
        ushort4 o;
        o.x = f2bf(acc[rt][0][r] + bsum[0]);
        o.y = f2bf(acc[rt][1][r] + bsum[1]);
        o.z = f2bf(acc[rt][2][r] + bsum[2]);
        o.w = f2bf(acc[rt][3][r] + bsum[3]);
        *(ushort4*)(xW4 + grow * 512 + colc * 4) = o;
      }
    }
}

// ---------------------------------------------------------------------------
// Kernel 2: LSTM recurrence. WG = 16 nodes, 8 waves; wave w owns h-cols
// [w*16, w*16+16). Whh B-fragments in registers. Depth-3 gather prefetch;
// h double-buffered in swizzled LDS -> one barrier per step; c in registers.
// ---------------------------------------------------------------------------
__global__ __launch_bounds__(512) void lstm_rec(
    const unsigned short* __restrict__ xW4,  // [N][128][4] bf16
    const int* __restrict__ src,             // [E]
    const float* __restrict__ Whh,           // [512,128] fp32
    float* __restrict__ agg) {               // [N,128] fp32
  __shared__ __align__(16) unsigned char hbuf[2][16 * 256];  // dbuf [16 nodes][128 bf16]
  __shared__ __align__(16) int idx_s[256];                   // idx_s[t*16 + node_local]
  const int tid = threadIdx.x;
  const int lane = tid & 63, w = tid >> 6;
  const int l15 = lane & 15, l4 = lane >> 4;
  const int node0 = blockIdx.x * 16;
  const int colb = w * 16 + l15;  // this lane's h-column

  // Whh B-fragments: B[k][n] = Whh[gate*128 + colb][k]
  bf16x8 bw[4][4];
#pragma unroll
  for (int g = 0; g < 4; ++g)
#pragma unroll
    for (int kt = 0; kt < 4; ++kt)
      bw[g][kt] = load_w8(Whh + (g * 128 + colb) * 128 + kt * 32 + l4 * 8);

  // stage edge indices transposed: idx_s[t*16 + node_local]
  if (tid < 256) idx_s[(tid & 15) * 16 + (tid >> 4)] = src[node0 * DEG + tid];
  __syncthreads();

  float c[4] = {0.f, 0.f, 0.f, 0.f};

  // depth-3 gather pipeline; each stage: 4 rows x (4 gates packed in uint2)
  uint2 xs[3][4];
#define ISSUE(T, S)                                                         \
  {                                                                         \
    int4 q = *(const int4*)(idx_s + (T) * 16 + l4 * 4);                     \
    xs[S][0] = *(const uint2*)(xW4 + q.x * 512 + colb * 4);                 \
    xs[S][1] = *(const uint2*)(xW4 + q.y * 512 + colb * 4);                 \
    xs[S][2] = *(const uint2*)(xW4 + q.z * 512 + colb * 4);                 \
    xs[S][3] = *(const uint2*)(xW4 + q.w * 512 + colb * 4);                 \
  }
  ISSUE(0, 0) ISSUE(1, 1) ISSUE(2, 2)

#pragma unroll
  for (int t = 0; t < 16; ++t) {
    const int s = t % 3;
    // acc init = xW pre-activation (gate order i,f,g,o packed lo/hi)
    f32x4 acc[4];
#pragma unroll
    for (int r = 0; r < 4; ++r) {
      unsigned lo = xs[s][r].x, hi = xs[s][r].y;
      acc[0][r] = __builtin_bit_cast(float, lo << 16);
      acc[1][r] = __builtin_bit_cast(float, lo & 0xffff0000u);
      acc[2][r] = __builtin_bit_cast(float, hi << 16);
      acc[3][r] = __builtin_bit_cast(float, hi & 0xffff0000u);
    }
    // refill this stage for t+3 (regs just consumed)
    if (t + 3 < 16) ISSUE(t + 3, s)

    if (t > 0) {  // h == 0 at t==0
      const unsigned char* hb = hbuf[(t - 1) & 1];
      bf16x8 af[4];
#pragma unroll
      for (int kt = 0; kt < 4; ++kt) {
        int byte = (l15 * 256 + kt * 64 + l4 * 16) ^ ((l15 & 7) << 4);
        af[kt] = *(const bf16x8*)(hb + byte);
      }
#pragma unroll
      for (int g = 0; g < 4; ++g)
#pragma unroll
        for (int kt = 0; kt < 4; ++kt)
          acc[g] = __builtin_amdgcn_mfma_f32_16x16x32_bf16(af[kt], bw[g][kt],
                                                           acc[g], 0, 0, 0);
    }

    // gates + state update (lane-local; gate tiles share C/D lane mapping)
    float hn[4];
#pragma unroll
    for (int r = 0; r < 4; ++r) {
      float ig = sigm(acc[0][r]), fg = sigm(acc[1][r]);
      float gg = tanh_(acc[2][r]), og = sigm(acc[3][r]);
      float cn = fg * c[r] + ig * gg;
      c[r] = cn;
      hn[r] = og * tanh_(cn);
    }

    if (t < 15) {
      unsigned char* hw = hbuf[t & 1];
#pragma unroll
      for (int r = 0; r < 4; ++r) {
        int m = l4 * 4 + r;
        int byte = (m * 256 + colb * 2) ^ ((m & 7) << 4);
        *(__bf16*)(hw + byte) = (__bf16)hn[r];
      }
      __syncthreads();  // h_t visible; also fences next write into other buf
    } else {
#pragma unroll
      for (int r = 0; r < 4; ++r)
        agg[(node0 + l4 * 4 + r) * 128 + colb] = hn[r];
    }
  }
#undef ISSUE
}

// ---------------------------------------------------------------------------
// Kernel 3: out[N,NOUT] = agg@Wl.T + bl + x@Wr.T (+resid) (+relu)
// Treated as one K=256 GEMM with A = [agg | x], B = [Wl | Wr].
// ---------------------------------------------------------------------------
__global__ __launch_bounds__(256) void gemm_out(
    const float* __restrict__ A1,   // agg [N,128]
    const float* __restrict__ A2,   // x   [N,128]
    const float* __restrict__ Wl, const float* __restrict__ bl,
    const float* __restrict__ Wr,
    const float* __restrict__ resid,  // nullptr or [N,128]
    float* __restrict__ out, int NOUT, int do_relu, int Nrows) {
  __shared__ __align__(16) unsigned char As[64 * 512];  // [64 rows][256 bf16], swizzled
  const int tid = threadIdx.x;
  const int lane = tid & 63, w = tid >> 6;
  const int l15 = lane & 15, l4 = lane >> 4;
  const int row0 = blockIdx.x * 64;

#pragma unroll
  for (int i = 0; i < 16; ++i) {
    int flat = i * 1024 + tid * 4;  // 0..16383
    int r = flat >> 8, c = flat & 255;
    int grow = row0 + r;
    float4 v;
    if (grow < Nrows)
      v = (c < 128) ? *(const float4*)(A1 + grow * 128 + c)
                    : *(const float4*)(A2 + grow * 128 + (c - 128));
    else
      v = make_float4(0.f, 0.f, 0.f, 0.f);
    ushort4 b;
    b.x = f2bf(v.x); b.y = f2bf(v.y); b.z = f2bf(v.z); b.w = f2bf(v.w);
    int byte = (r * 512 + c * 2) ^ ((r & 7) << 4);
    *(ushort4*)(As + byte) = b;
  }
  __syncthreads();

  const int colg = blockIdx.y * 64 + w * 16 + l15;
  bf16x8 bw[8];
#pragma unroll
  for (int kt = 0; kt < 8; ++kt) {
    const float* bp = (kt < 4) ? (Wl + colg * 128 + kt * 32 + l4 * 8)
                               : (Wr + colg * 128 + (kt - 4) * 32 + l4 * 8);
    bw[kt] = load_w8(bp);
  }

  f32x4 acc[4];
#pragma unroll
  for (int rt = 0; rt < 4; ++rt) acc[rt] = (f32x4){0.f, 0.f, 0.f, 0.f};

#pragma unroll
  for (int kt = 0; kt < 8; ++kt) {
#pragma unroll
    for (int rt = 0; rt < 4; ++rt) {
      int m = rt * 16 + l15;
      int byte = (m * 512 + kt * 64 + l4 * 16) ^ ((m & 7) << 4);
      bf16x8 af = *(const bf16x8*)(As + byte);
      acc[rt] = __builtin_amdgcn_mfma_f32_16x16x32_bf16(af, bw[kt], acc[rt], 0, 0, 0);
    }
  }

  const float bias = bl[colg];
#pragma unroll
  for (int rt = 0; rt < 4; ++rt)
#pragma unroll
    for (int r = 0; r < 4; ++r) {
      int grow = row0 + rt * 16 + l4 * 4 + r;
      if (grow < Nrows) {
        float v = acc[rt][r] + bias;
        if (resid) v += resid[grow * 128 + colg];
        if (do_relu) v = fmaxf(v, 0.f);
        out[grow * NOUT + colg] = v;
      }
    }
}

// ---------------------------------------------------------------------------
extern "C" void kernel_launch(void* const* d_in, const int* in_sizes, int n_in,
                              void* d_out, int out_size, void* d_ws, size_t ws_size,
                              hipStream_t stream) {
  const float* X = (const float*)d_in[0];
  const int* src = (const int*)d_in[1];  // edge_index[0] = first E ints
  const float* Wih = (const float*)d_in[2];
  const float* Whh = (const float*)d_in[3];
  const float* bih = (const float*)d_in[4];
  const float* bhh = (const float*)d_in[5];
  const float* Wl123 = (const float*)d_in[6];
  const float* bl123 = (const float*)d_in[7];
  const float* Wr123 = (const float*)d_in[8];
  const float* Wl4 = (const float*)d_in[9];
  const float* bl4 = (const float*)d_in[10];
  const float* Wr4 = (const float*)d_in[11];
  float* out = (float*)d_out;

  char* ws = (char*)d_ws;
  unsigned short* xW4 = (unsigned short*)ws;                      // 20.48 MB
  float* agg = (float*)(ws + 20480000);                           // 10.24 MB
  float* xb0 = (float*)(ws + 20480000 + 10240000);                // 10.24 MB
  float* xb1 = (float*)(ws + 20480000 + 2 * 10240000);            // 10.24 MB

  const float* xcur = X;
  for (int L = 0; L < 4; ++L) {
    gemm_xw<<<dim3(313, 2), 256, 0, stream>>>(xcur, Wih + L * 65536, bih + L * 512,
                                              bhh + L * 512, xW4, N_NODES);
    lstm_rec<<<dim3(1250), 512, 0, stream>>>(xW4, src, Whh + L * 65536, agg);
    if (L < 3) {
      float* nxt = (L & 1) ? xb1 : xb0;
      gemm_out<<<dim3(313, 2), 256, 0, stream>>>(agg, xcur, Wl123 + L * 16384,
                                                 bl123 + L * 128, Wr123 + L * 16384,
                                                 (L >= 1) ? xcur : nullptr, nxt, 128, 1,
                                                 N_NODES);
      xcur = nxt;
    } else {
      gemm_out<<<dim3(313, 1), 256, 0, stream>>>(agg, xcur, Wl4, bl4, Wr4, nullptr, out,
                                                 64, 0, N_NODES);
    }
  }
}

// Round 4
// 563.486 us; speedup vs baseline: 1.2173x; 1.0610x over previous
//
#include <hip/hip_runtime.h>

// ImprovedGraphSAGE: 4x SAGEConv(aggr='lstm') on MI355X.
// N=20000 nodes, DEG=16, F_IN=HID=128, OUT=64, E=320000.
//
// R4 structure (gather-bytes reduction: 1KB/edge -> 256B/edge):
//   0) prep_weights: Wih,Whh -> bf16; bsum = bih+bhh     (once)
//   1) cast_bf     : xbf = bf16(x)                       (layer 0 only)
//   2) lstm_fused  : stage 256 gathered xbf rows in LDS up front;
//                    16 steps of gates = x_t@Wih.T + h@Whh.T + b, all MFMA,
//                    Wih+Whh B-frags in regs, h dbuf in LDS (1 barrier/step)
//   3) gemm_out    : y = agg@Wl.T + bl + x@Wr.T (+res)(+relu), dual fp32+bf16

#define N_NODES 20000
#define DEG 16

typedef __bf16 bf16x8 __attribute__((ext_vector_type(8)));
typedef float f32x4 __attribute__((ext_vector_type(4)));

__device__ inline unsigned short f2bf(float f) {
  unsigned u = __builtin_bit_cast(unsigned, f);
  u += 0x7fffu + ((u >> 16) & 1u);
  return (unsigned short)(u >> 16);
}
__device__ inline float fexp2(float x) {
#if __has_builtin(__builtin_amdgcn_exp2f)
  return __builtin_amdgcn_exp2f(x);
#else
  return exp2f(x);
#endif
}
__device__ inline float frcp(float x) {
#if __has_builtin(__builtin_amdgcn_rcpf)
  return __builtin_amdgcn_rcpf(x);
#else
  return 1.f / x;
#endif
}
__device__ inline float sigm(float x) { return frcp(1.f + fexp2(-1.44269504f * x)); }
__device__ inline float tanh_(float x) { return frcp(1.f + fexp2(-2.88539008f * x)) * 2.f - 1.f; }

// ---------------------------------------------------------------------------
// prep: weights fp32 -> bf16 (all 4 layers), bsum = bih + bhh
// Wih/Whh each 4*512*128 = 262144 elems = 65536 float4 tasks; grid 256x256.
// ---------------------------------------------------------------------------
__global__ __launch_bounds__(256) void prep_weights(
    const float* __restrict__ Wih, const float* __restrict__ Whh,
    const float* __restrict__ bih, const float* __restrict__ bhh,
    unsigned short* __restrict__ WihB, unsigned short* __restrict__ WhhB,
    float* __restrict__ bsum) {
  int tid = blockIdx.x * 256 + threadIdx.x;  // 0..65535
  float4 a = *(const float4*)(Wih + tid * 4);
  ushort4 o;
  o.x = f2bf(a.x); o.y = f2bf(a.y); o.z = f2bf(a.z); o.w = f2bf(a.w);
  *(ushort4*)(WihB + tid * 4) = o;
  float4 b = *(const float4*)(Whh + tid * 4);
  ushort4 p;
  p.x = f2bf(b.x); p.y = f2bf(b.y); p.z = f2bf(b.z); p.w = f2bf(b.w);
  *(ushort4*)(WhhB + tid * 4) = p;
  if (tid < 2048) bsum[tid] = bih[tid] + bhh[tid];
}

// ---------------------------------------------------------------------------
// cast: xbf = bf16(x), 640000 float4 tasks, grid 2500x256
// ---------------------------------------------------------------------------
__global__ __launch_bounds__(256) void cast_bf(
    const float* __restrict__ x, unsigned short* __restrict__ xb) {
  int tid = blockIdx.x * 256 + threadIdx.x;
  float4 v = *(const float4*)(x + tid * 4);
  ushort4 o;
  o.x = f2bf(v.x); o.y = f2bf(v.y); o.z = f2bf(v.z); o.w = f2bf(v.w);
  *(ushort4*)(xb + tid * 4) = o;
}

// ---------------------------------------------------------------------------
// lstm_fused: WG = 16 nodes, 8 waves; wave w owns gate-cols {g*128 + w*16+l15}.
// Stage all 256 gathered x rows (bf16, 256B each) into LDS up front, then
// 16 steps with zero global traffic: acc = bias; acc += x_t@Wih.T (MFMA);
// acc += h@Whh.T (MFMA); activations; h through dbuf LDS, 1 barrier/step.
// ---------------------------------------------------------------------------
__global__ __launch_bounds__(512) void lstm_fused(
    const unsigned short* __restrict__ xbf,   // [N][128] bf16
    const int* __restrict__ src,              // [E]
    const unsigned short* __restrict__ WihB,  // [512][128] bf16 (layer slice)
    const unsigned short* __restrict__ WhhB,  // [512][128] bf16
    const float* __restrict__ bsum,           // [512]
    float* __restrict__ agg) {                // [N,128] fp32
  __shared__ __align__(16) unsigned char xs[256 * 256];      // 64KB staged x rows
  __shared__ __align__(16) unsigned char hbuf[2][16 * 256];  // 8KB h double-buffer
  __shared__ __align__(16) int idx_s[256];                   // idx_s[t*16 + node]
  const int tid = threadIdx.x;
  const int lane = tid & 63, w = tid >> 6;
  const int l15 = lane & 15, l4 = lane >> 4;
  const int node0 = blockIdx.x * 16;
  const int colb = w * 16 + l15;  // this wave-lane's output column (per gate)

  // edge indices, transposed to [t][node]
  if (tid < 256) idx_s[(tid & 15) * 16 + (tid >> 4)] = src[node0 * DEG + tid];
  __syncthreads();

  // stage 256 gathered x rows: wave w stages rows e = w*32..w*32+31,
  // quarter-wave (16 lanes x 16B) per row -> 4 rows per instruction.
#pragma unroll
  for (int it = 0; it < 8; ++it) {
    int e = w * 32 + it * 4 + l4;
    int idx = idx_s[e];
    uint4 v = *(const uint4*)(xbf + idx * 128 + l15 * 8);
    int byte = (e * 256 + l15 * 16) ^ ((e & 7) << 4);
    *(uint4*)(xs + byte) = v;
  }

  // weight B-fragments (bf16, already converted): B[k][n]=W[gate*128+colb][k]
  bf16x8 bwx[4][4], bwh[4][4];
  float bs[4];
#pragma unroll
  for (int g = 0; g < 4; ++g) {
#pragma unroll
    for (int kt = 0; kt < 4; ++kt) {
      bwx[g][kt] = *(const bf16x8*)(WihB + (g * 128 + colb) * 128 + kt * 32 + l4 * 8);
      bwh[g][kt] = *(const bf16x8*)(WhhB + (g * 128 + colb) * 128 + kt * 32 + l4 * 8);
    }
    bs[g] = bsum[g * 128 + colb];
  }
  __syncthreads();  // xs visible to all

  float c[4] = {0.f, 0.f, 0.f, 0.f};

#pragma unroll
  for (int t = 0; t < 16; ++t) {
    f32x4 acc[4];
#pragma unroll
    for (int g = 0; g < 4; ++g) acc[g] = (f32x4){bs[g], bs[g], bs[g], bs[g]};

    // x-part: A rows = staged rows e = t*16 + node(l15)
    {
      bf16x8 afx[4];
#pragma unroll
      for (int kt = 0; kt < 4; ++kt) {
        int e = t * 16 + l15;
        int byte = (e * 256 + kt * 64 + l4 * 16) ^ ((e & 7) << 4);
        afx[kt] = *(const bf16x8*)(xs + byte);
      }
#pragma unroll
      for (int g = 0; g < 4; ++g)
#pragma unroll
        for (int kt = 0; kt < 4; ++kt)
          acc[g] = __builtin_amdgcn_mfma_f32_16x16x32_bf16(afx[kt], bwx[g][kt],
                                                           acc[g], 0, 0, 0);
    }

    // h-part (h == 0 at t==0)
    if (t > 0) {
      const unsigned char* hb = hbuf[(t - 1) & 1];
      bf16x8 afh[4];
#pragma unroll
      for (int kt = 0; kt < 4; ++kt) {
        int byte = (l15 * 256 + kt * 64 + l4 * 16) ^ ((l15 & 7) << 4);
        afh[kt] = *(const bf16x8*)(hb + byte);
      }
#pragma unroll
      for (int g = 0; g < 4; ++g)
#pragma unroll
        for (int kt = 0; kt < 4; ++kt)
          acc[g] = __builtin_amdgcn_mfma_f32_16x16x32_bf16(afh[kt], bwh[g][kt],
                                                           acc[g], 0, 0, 0);
    }

    // gates + state update (lane-local; gate tiles share C/D lane mapping)
    float hn[4];
#pragma unroll
    for (int r = 0; r < 4; ++r) {
      float ig = sigm(acc[0][r]), fg = sigm(acc[1][r]);
      float gg = tanh_(acc[2][r]), og = sigm(acc[3][r]);
      float cn = fg * c[r] + ig * gg;
      c[r] = cn;
      hn[r] = og * tanh_(cn);
    }

    if (t < 15) {
      unsigned char* hw = hbuf[t & 1];
#pragma unroll
      for (int r = 0; r < 4; ++r) {
        int m = l4 * 4 + r;
        int byte = (m * 256 + colb * 2) ^ ((m & 7) << 4);
        *(__bf16*)(hw + byte) = (__bf16)hn[r];
      }
      __syncthreads();  // h_t visible; also fences next write into other buf
    } else {
#pragma unroll
      for (int r = 0; r < 4; ++r)
        agg[(node0 + l4 * 4 + r) * 128 + colb] = hn[r];
    }
  }
}

// ---------------------------------------------------------------------------
// gemm_out: out[N,NOUT] = agg@Wl.T + bl + x@Wr.T (+resid) (+relu)
// One K=256 GEMM with A = [agg | x], B = [Wl | Wr]. Optionally dual-writes
// bf16 copy (next layer's gather source).
// ---------------------------------------------------------------------------
__global__ __launch_bounds__(256) void gemm_out(
    const float* __restrict__ A1,   // agg [N,128]
    const float* __restrict__ A2,   // x   [N,128]
    const float* __restrict__ Wl, const float* __restrict__ bl,
    const float* __restrict__ Wr,
    const float* __restrict__ resid,    // nullptr or [N,128]
    float* __restrict__ out,
    unsigned short* __restrict__ outbf,  // nullptr or [N,128] bf16
    int NOUT, int do_relu, int Nrows) {
  __shared__ __align__(16) unsigned char As[64 * 512];  // [64 rows][256 bf16], swizzled
  const int tid = threadIdx.x;
  const int lane = tid & 63, w = tid >> 6;
  const int l15 = lane & 15, l4 = lane >> 4;
  const int row0 = blockIdx.x * 64;

#pragma unroll
  for (int i = 0; i < 16; ++i) {
    int flat = i * 1024 + tid * 4;  // 0..16383
    int r = flat >> 8, c = flat & 255;
    int grow = row0 + r;
    float4 v;
    if (grow < Nrows)
      v = (c < 128) ? *(const float4*)(A1 + grow * 128 + c)
                    : *(const float4*)(A2 + grow * 128 + (c - 128));
    else
      v = make_float4(0.f, 0.f, 0.f, 0.f);
    ushort4 b;
    b.x = f2bf(v.x); b.y = f2bf(v.y); b.z = f2bf(v.z); b.w = f2bf(v.w);
    int byte = (r * 512 + c * 2) ^ ((r & 7) << 4);
    *(ushort4*)(As + byte) = b;
  }
  __syncthreads();

  const int colg = blockIdx.y * 64 + w * 16 + l15;
  bf16x8 bw[8];
#pragma unroll
  for (int kt = 0; kt < 8; ++kt) {
    const float* bp = (kt < 4) ? (Wl + colg * 128 + kt * 32 + l4 * 8)
                               : (Wr + colg * 128 + (kt - 4) * 32 + l4 * 8);
    float4 a = *(const float4*)bp;
    float4 b = *(const float4*)(bp + 4);
    bf16x8 v;
    v[0] = (__bf16)a.x; v[1] = (__bf16)a.y; v[2] = (__bf16)a.z; v[3] = (__bf16)a.w;
    v[4] = (__bf16)b.x; v[5] = (__bf16)b.y; v[6] = (__bf16)b.z; v[7] = (__bf16)b.w;
    bw[kt] = v;
  }

  f32x4 acc[4];
#pragma unroll
  for (int rt = 0; rt < 4; ++rt) acc[rt] = (f32x4){0.f, 0.f, 0.f, 0.f};

#pragma unroll
  for (int kt = 0; kt < 8; ++kt) {
#pragma unroll
    for (int rt = 0; rt < 4; ++rt) {
      int m = rt * 16 + l15;
      int byte = (m * 512 + kt * 64 + l4 * 16) ^ ((m & 7) << 4);
      bf16x8 af = *(const bf16x8*)(As + byte);
      acc[rt] = __builtin_amdgcn_mfma_f32_16x16x32_bf16(af, bw[kt], acc[rt], 0, 0, 0);
    }
  }

  const float bias = bl[colg];
#pragma unroll
  for (int rt = 0; rt < 4; ++rt)
#pragma unroll
    for (int r = 0; r < 4; ++r) {
      int grow = row0 + rt * 16 + l4 * 4 + r;
      if (grow < Nrows) {
        float v = acc[rt][r] + bias;
        if (resid) v += resid[grow * 128 + colg];
        if (do_relu) v = fmaxf(v, 0.f);
        out[grow * NOUT + colg] = v;
        if (outbf) outbf[grow * 128 + colg] = f2bf(v);
      }
    }
}

// ---------------------------------------------------------------------------
extern "C" void kernel_launch(void* const* d_in, const int* in_sizes, int n_in,
                              void* d_out, int out_size, void* d_ws, size_t ws_size,
                              hipStream_t stream) {
  const float* X = (const float*)d_in[0];
  const int* src = (const int*)d_in[1];  // edge_index[0] = first E ints
  const float* Wih = (const float*)d_in[2];
  const float* Whh = (const float*)d_in[3];
  const float* bih = (const float*)d_in[4];
  const float* bhh = (const float*)d_in[5];
  const float* Wl123 = (const float*)d_in[6];
  const float* bl123 = (const float*)d_in[7];
  const float* Wr123 = (const float*)d_in[8];
  const float* Wl4 = (const float*)d_in[9];
  const float* bl4 = (const float*)d_in[10];
  const float* Wr4 = (const float*)d_in[11];
  float* out = (float*)d_out;

  char* ws = (char*)d_ws;
  unsigned short* xbf = (unsigned short*)ws;                 // 5.12 MB
  float* agg = (float*)(ws + 5120000);                       // 10.24 MB
  float* xb0 = (float*)(ws + 15360000);                      // 10.24 MB
  float* xb1 = (float*)(ws + 25600000);                      // 10.24 MB
  unsigned short* WihB = (unsigned short*)(ws + 35840000);   // 0.52 MB
  unsigned short* WhhB = (unsigned short*)(ws + 36364288);   // 0.52 MB
  float* bsumW = (float*)(ws + 36888576);                    // 8 KB

  prep_weights<<<dim3(256), 256, 0, stream>>>(Wih, Whh, bih, bhh, WihB, WhhB, bsumW);
  cast_bf<<<dim3(2500), 256, 0, stream>>>(X, xbf);

  const float* xcur = X;
  for (int L = 0; L < 4; ++L) {
    lstm_fused<<<dim3(1250), 512, 0, stream>>>(xbf, src, WihB + L * 65536,
                                               WhhB + L * 65536, bsumW + L * 512, agg);
    if (L < 3) {
      float* nxt = (L & 1) ? xb1 : xb0;
      gemm_out<<<dim3(313, 2), 256, 0, stream>>>(agg, xcur, Wl123 + L * 16384,
                                                 bl123 + L * 128, Wr123 + L * 16384,
                                                 (L >= 1) ? xcur : nullptr, nxt, xbf,
                                                 128, 1, N_NODES);
      xcur = nxt;
    } else {
      gemm_out<<<dim3(313, 1), 256, 0, stream>>>(agg, xcur, Wl4, bl4, Wr4, nullptr, out,
                                                 nullptr, 64, 0, N_NODES);
    }
  }
}